// Round 10
// baseline (42.825 us; speedup 1.0000x reference)
//
#include <hip/hip_runtime.h>
#include <hip/hip_bf16.h>
#include <math.h>

typedef float  f32x4  __attribute__((ext_vector_type(4)));
typedef short  s16x4  __attribute__((ext_vector_type(4)));
typedef short  s16x8  __attribute__((ext_vector_type(8)));
typedef unsigned short u16;

__device__ inline u16 f2b(float f) {
    __hip_bfloat16 h = __float2bfloat16(f);
    return *reinterpret_cast<u16*>(&h);
}

// ---------------------------------------------------------------------------
// K0: prep. blocks 0-191: transpose-cast weights -> Wt [1024][512] bf16
// (rows 0-511 Wq^T | 512-767 Wk^T | 768-1023 Wv^T), Wot [512][512] = Wo^T.
// blocks 192-703: cast x -> xb bf16 (8 elems/thread, vectorized).
// ---------------------------------------------------------------------------
__global__ __launch_bounds__(256) void prep(const float* __restrict__ x,
    const float* __restrict__ Wq, const float* __restrict__ Wk,
    const float* __restrict__ Wv, const float* __restrict__ Wo,
    u16* __restrict__ xb, u16* __restrict__ Wt, u16* __restrict__ Wot)
{
    const int tid = threadIdx.x, bid = blockIdx.x;
    if (bid >= 192) {   // x cast
        int i = ((bid - 192) * 256 + tid) * 8;
        float4 v0 = *(const float4*)(x + i);
        float4 v1 = *(const float4*)(x + i + 4);
        ushort4 o0 = { f2b(v0.x), f2b(v0.y), f2b(v0.z), f2b(v0.w) };
        ushort4 o1 = { f2b(v1.x), f2b(v1.y), f2b(v1.z), f2b(v1.w) };
        *(ushort4*)(xb + i)     = o0;
        *(ushort4*)(xb + i + 4) = o1;
        return;
    }
    __shared__ u16 Tsh[64][72];
    const float* src; u16* dst; int N, base, kt, nt;
    if (bid < 64)       { src = Wq; dst = Wt;  N = 512; base = 0;   kt = bid >> 3;       nt = bid & 7; }
    else if (bid < 96)  { src = Wk; dst = Wt;  N = 256; base = 512; kt = (bid-64) >> 2;  nt = (bid-64) & 3; }
    else if (bid < 128) { src = Wv; dst = Wt;  N = 256; base = 768; kt = (bid-96) >> 2;  nt = (bid-96) & 3; }
    else                { src = Wo; dst = Wot; N = 512; base = 0;   kt = (bid-128) >> 3; nt = (bid-128) & 7; }
    const int k0 = kt * 64, n0 = nt * 64;
    const int r = tid >> 2, c0 = (tid & 3) * 16;
#pragma unroll
    for (int j = 0; j < 4; ++j) {
        float4 v = *(const float4*)(src + (size_t)(k0 + r) * N + n0 + c0 + j * 4);
        Tsh[c0 + j*4 + 0][r] = f2b(v.x);
        Tsh[c0 + j*4 + 1][r] = f2b(v.y);
        Tsh[c0 + j*4 + 2][r] = f2b(v.z);
        Tsh[c0 + j*4 + 3][r] = f2b(v.w);
    }
    __syncthreads();
    const int n = tid >> 2, kc = (tid & 3) * 16;
    u16* op = dst + (size_t)(base + n0 + n) * 512 + k0 + kc;
    *(s16x8*)(op)     = *(const s16x8*)&Tsh[n][kc];
    *(s16x8*)(op + 8) = *(const s16x8*)&Tsh[n][kc + 8];
}

// ---------------------------------------------------------------------------
// bf16 MFMA GEMM, B-direct-from-global variant: C[M x N] f32 = A bf16 @
// Bt[N][512] bf16. A staged in LDS (reused across waves); B fragments loaded
// straight from global per wave (weights are L1/L2-resident; fragment = lane
// q reads 16 contiguous bytes of row n0+wn+q — identical bits to LDS path).
// Halves LDS reads and staging writes; LDS = 9 KB.
// ---------------------------------------------------------------------------
__global__ __launch_bounds__(256) void gemm_mfma(const u16* __restrict__ A,
    const u16* __restrict__ Bt, float* __restrict__ C, int ldc)
{
    __shared__ u16 Ash[64][72];
    const int tid = threadIdx.x;
    const int m0b = blockIdx.y * 64, n0b = blockIdx.x * 64;
    const int lane = tid & 63, wv = tid >> 6;
    const int q = lane & 15, g = lane >> 4;
    const int wm = (wv & 1) * 32, wn = (wv >> 1) * 32;
    const int sr = tid >> 2, sc = (tid & 3) * 16;
    const u16* Brow0 = Bt + (size_t)(n0b + wn + q)      * 512 + g * 8;
    const u16* Brow1 = Bt + (size_t)(n0b + wn + 16 + q) * 512 + g * 8;
    f32x4 acc[2][2] = {{{0,0,0,0},{0,0,0,0}},{{0,0,0,0},{0,0,0,0}}};
    for (int k0 = 0; k0 < 512; k0 += 64) {
        s16x8 a0 = *(const s16x8*)(A + (size_t)(m0b + sr) * 512 + k0 + sc);
        s16x8 a1 = *(const s16x8*)(A + (size_t)(m0b + sr) * 512 + k0 + sc + 8);
        s16x8 bf0_0 = *(const s16x8*)(Brow0 + k0);
        s16x8 bf1_0 = *(const s16x8*)(Brow1 + k0);
        s16x8 bf0_1 = *(const s16x8*)(Brow0 + k0 + 32);
        s16x8 bf1_1 = *(const s16x8*)(Brow1 + k0 + 32);
        __syncthreads();
        *(s16x8*)&Ash[sr][sc]     = a0;
        *(s16x8*)&Ash[sr][sc + 8] = a1;
        __syncthreads();
        {
            s16x8 af0 = *(const s16x8*)&Ash[wm + q][g*8];
            s16x8 af1 = *(const s16x8*)&Ash[wm + 16 + q][g*8];
            acc[0][0] = __builtin_amdgcn_mfma_f32_16x16x32_bf16(af0, bf0_0, acc[0][0], 0, 0, 0);
            acc[0][1] = __builtin_amdgcn_mfma_f32_16x16x32_bf16(af0, bf1_0, acc[0][1], 0, 0, 0);
            acc[1][0] = __builtin_amdgcn_mfma_f32_16x16x32_bf16(af1, bf0_0, acc[1][0], 0, 0, 0);
            acc[1][1] = __builtin_amdgcn_mfma_f32_16x16x32_bf16(af1, bf1_0, acc[1][1], 0, 0, 0);
        }
        {
            s16x8 af0 = *(const s16x8*)&Ash[wm + q][32 + g*8];
            s16x8 af1 = *(const s16x8*)&Ash[wm + 16 + q][32 + g*8];
            acc[0][0] = __builtin_amdgcn_mfma_f32_16x16x32_bf16(af0, bf0_1, acc[0][0], 0, 0, 0);
            acc[0][1] = __builtin_amdgcn_mfma_f32_16x16x32_bf16(af0, bf1_1, acc[0][1], 0, 0, 0);
            acc[1][0] = __builtin_amdgcn_mfma_f32_16x16x32_bf16(af1, bf0_1, acc[1][0], 0, 0, 0);
            acc[1][1] = __builtin_amdgcn_mfma_f32_16x16x32_bf16(af1, bf1_1, acc[1][1], 0, 0, 0);
        }
    }
#pragma unroll
    for (int mt = 0; mt < 2; ++mt)
#pragma unroll
        for (int nt = 0; nt < 2; ++nt)
#pragma unroll
            for (int r = 0; r < 4; ++r)
                C[(size_t)(m0b + wm + mt*16 + g*4 + r) * ldc + n0b + wn + nt*16 + q] = acc[mt][nt][r];
}

// ---------------------------------------------------------------------------
// RoPE + RMS -> bf16 Q/K; V cast -> bf16 (verified). One wave per (t, unit);
// units 0-7 q-heads, 8-11 k-heads, 12-15 v-cast. qkv f32 [T][1024].
// ---------------------------------------------------------------------------
__global__ __launch_bounds__(256) void rope_rms_b(const float* __restrict__ qkv,
    const float* __restrict__ cosT, const float* __restrict__ sinT,
    const float* __restrict__ qw, const float* __restrict__ kw,
    u16* __restrict__ qnb, u16* __restrict__ knb, u16* __restrict__ vb)
{
    const int lane = threadIdx.x & 63;
    const int gid  = blockIdx.x * 4 + (threadIdx.x >> 6);
    const int t = gid >> 4, hh = gid & 15;
    if (hh >= 12) {
        int vh = hh - 12;
        vb[(size_t)t * 256 + vh * 64 + lane] =
            f2b(qkv[(size_t)t * 1024 + 768 + vh * 64 + lane]);
        return;
    }
    const float* src; u16* dst; const float* nw;
    if (hh < 8) { src = qkv + (size_t)t*1024 + hh*64;           dst = qnb + (size_t)t*512 + hh*64;     nw = qw; }
    else        { src = qkv + (size_t)t*1024 + 512 + (hh-8)*64; dst = knb + (size_t)t*256 + (hh-8)*64; nw = kw; }
    float y = src[lane];
    float o = __shfl(y, lane ^ 32);
    float c = cosT[t * 32 + (lane & 31)];
    float s = sinT[t * 32 + (lane & 31)];
    float r = (lane < 32) ? (y * c - o * s) : (y * c + o * s);
    float ss = r * r;
#pragma unroll
    for (int off = 32; off; off >>= 1) ss += __shfl_xor(ss, off);
    dst[lane] = f2b(r * rsqrtf(ss * (1.0f/64.0f) + 1e-6f) * nw[lane]);
}

// ---------------------------------------------------------------------------
// swa: MFMA sliding-window attention (verified; Vt stride 202 = odd dword
// stride -> spread banks on PV reads). Block = (h, 64-q tile), 4 waves.
// S^T = K·Q^T (16x16x32); P^T rows land in 16x16x16 k-operand layout;
// O^T = V^T·P^T; LDS transpose out.
// ---------------------------------------------------------------------------
__global__ __launch_bounds__(256) void swa_mfma(const u16* __restrict__ qnb,
    const u16* __restrict__ knb, const u16* __restrict__ vb,
    u16* __restrict__ attb)
{
    __shared__ u16 Ksh[192][72];
    __shared__ u16 Vt[64][202];
    const int tid = threadIdx.x;
    const int h = blockIdx.y, kvh = h >> 1;
    const int t0 = blockIdx.x * 64;
    for (int i = 0; i < 6; ++i) {
        int idx = i * 256 + tid;
        int j = idx >> 3, d0 = (idx & 7) * 8;
        int kt = t0 - 127 + j;
        s16x8 val = {0,0,0,0,0,0,0,0};
        if (kt >= 0) val = *(const s16x8*)(knb + (size_t)kt * 256 + kvh * 64 + d0);
        *(s16x8*)&Ksh[j][d0] = val;
    }
    for (int cch = 0; cch < 6; ++cch) {
        int w  = cch * 32 + (tid & 31);
        int d0 = (tid >> 5) * 8;
        int kt = t0 - 127 + w;
        s16x8 val = {0,0,0,0,0,0,0,0};
        if (kt >= 0) val = *(const s16x8*)(vb + (size_t)kt * 256 + kvh * 64 + d0);
#pragma unroll
        for (int jj = 0; jj < 8; ++jj) Vt[d0 + jj][w] = ((const u16*)&val)[jj];
    }
    __syncthreads();
    const int wv = tid >> 6, lane = tid & 63;
    const int q = lane & 15, g = lane >> 4;
    const int tw = t0 + wv * 16;
    const int t = tw + q;
    const u16* qp = qnb + (size_t)t * 512 + h * 64;
    s16x8 qf0 = *(const s16x8*)(qp + g * 8);
    s16x8 qf1 = *(const s16x8*)(qp + 32 + g * 8);
    float s[9][4];
    float mx = -INFINITY;
    for (int wt = 0; wt < 9; ++wt) {
        int ldsrow = wv * 16 + wt * 16 + q;
        s16x8 kf0 = *(const s16x8*)&Ksh[ldsrow][g * 8];
        s16x8 kf1 = *(const s16x8*)&Ksh[ldsrow][32 + g * 8];
        f32x4 accv = {0, 0, 0, 0};
        accv = __builtin_amdgcn_mfma_f32_16x16x32_bf16(kf0, qf0, accv, 0, 0, 0);
        accv = __builtin_amdgcn_mfma_f32_16x16x32_bf16(kf1, qf1, accv, 0, 0, 0);
#pragma unroll
        for (int r = 0; r < 4; ++r) {
            int woff = wt * 16 + g * 4 + r;
            int key  = tw - 127 + woff;
            bool ok = (woff >= q) && (woff <= q + 127) && (key >= 0);
            float sv = ok ? accv[r] * 0.125f : -INFINITY;
            s[wt][r] = sv;
            mx = fmaxf(mx, sv);
        }
    }
    mx = fmaxf(mx, __shfl_xor(mx, 16));
    mx = fmaxf(mx, __shfl_xor(mx, 32));
    float sum = 0.f;
    s16x4 pb[9];
    for (int wt = 0; wt < 9; ++wt) {
#pragma unroll
        for (int r = 0; r < 4; ++r) {
            float p = __expf(s[wt][r] - mx);
            sum += p;
            pb[wt][r] = (short)f2b(p);
        }
    }
    sum += __shfl_xor(sum, 16);
    sum += __shfl_xor(sum, 32);
    float inv = 1.0f / sum;
    f32x4 oacc[4];
#pragma unroll
    for (int dt = 0; dt < 4; ++dt) {
        f32x4 a = {0, 0, 0, 0};
        for (int wt = 0; wt < 9; ++wt) {
            int col = wv * 16 + wt * 16 + g * 4;
            s16x4 vf = *(const s16x4*)&Vt[dt * 16 + q][col];
            a = __builtin_amdgcn_mfma_f32_16x16x16bf16_1k(vf, pb[wt], a, 0, 0, 0);
        }
        oacc[dt] = a;
    }
    __syncthreads();
    float (*Osh)[16][68] = (float (*)[16][68])&Ksh[0][0];
#pragma unroll
    for (int dt = 0; dt < 4; ++dt)
#pragma unroll
        for (int r = 0; r < 4; ++r)
            Osh[wv][q][dt * 16 + g * 4 + r] = oacc[dt][r] * inv;
    __syncthreads();
    const int qq = lane >> 2, dd0 = (lane & 3) * 16;
    u16* op = attb + (size_t)(tw + qq) * 512 + h * 64 + dd0;
#pragma unroll
    for (int jj = 0; jj < 4; ++jj) {
        float4 vvv = *(const float4*)&Osh[wv][qq][dd0 + jj * 4];
        ushort4 ov = { f2b(vvv.x), f2b(vvv.y), f2b(vvv.z), f2b(vvv.w) };
        *(ushort4*)(op + jj * 4) = ov;
    }
}

// ---------------------------------------------------------------------------
// Workspace: xb [2048*512 u16] | Wt [1024*512] | Wot [512*512] |
//            qkv f32 [2048*1024] | qnb [2048*512] | knb [2048*256] |
//            vb [2048*256] | attb [2048*512]   ≈ 17.5 MB
// ---------------------------------------------------------------------------
extern "C" void kernel_launch(void* const* d_in, const int* in_sizes, int n_in,
                              void* d_out, int out_size, void* d_ws, size_t ws_size,
                              hipStream_t stream)
{
    const float* x    = (const float*)d_in[0];
    const float* Wq   = (const float*)d_in[1];
    const float* Wk   = (const float*)d_in[2];
    const float* Wv   = (const float*)d_in[3];
    const float* Wo   = (const float*)d_in[4];
    const float* qw   = (const float*)d_in[5];
    const float* kw   = (const float*)d_in[6];
    const float* cosT = (const float*)d_in[7];
    const float* sinT = (const float*)d_in[8];

    u16* ws   = (u16*)d_ws;
    u16* xb   = ws;                               // 2048*512
    u16* Wt   = xb  + (size_t)2048 * 512;         // 1024*512
    u16* Wot  = Wt  + (size_t)1024 * 512;         // 512*512
    float* qkv = (float*)(Wot + (size_t)512 * 512);  // 2048*1024 f32 (8B-aligned)
    u16* qnb  = (u16*)(qkv + (size_t)2048 * 1024);   // 2048*512
    u16* knb  = qnb + (size_t)2048 * 512;         // 2048*256
    u16* vb   = knb + (size_t)2048 * 256;         // 2048*256
    u16* attb = vb  + (size_t)2048 * 256;         // 2048*512

    dim3 blk(256);
    hipLaunchKernelGGL(prep, dim3(704), blk, 0, stream, x, Wq, Wk, Wv, Wo, xb, Wt, Wot);
    hipLaunchKernelGGL(gemm_mfma, dim3(16, 32), blk, 0, stream, xb, Wt, qkv, 1024);
    hipLaunchKernelGGL(rope_rms_b, dim3(8192), blk, 0, stream,
                       qkv, cosT, sinT, qw, kw, qnb, knb, vb);
    hipLaunchKernelGGL(swa_mfma, dim3(32, 8), blk, 0, stream, qnb, knb, vb, attb);
    hipLaunchKernelGGL(gemm_mfma, dim3(8, 32), blk, 0, stream, attb, Wot, (float*)d_out, 512);
}

// Round 11
// 35.473 us; speedup vs baseline: 1.2073x; 1.2073x over previous
//
#include <hip/hip_runtime.h>
#include <hip/hip_bf16.h>
#include <math.h>

typedef float  f32x4  __attribute__((ext_vector_type(4)));
typedef short  s16x4  __attribute__((ext_vector_type(4)));
typedef short  s16x8  __attribute__((ext_vector_type(8)));
typedef unsigned short u16;

__device__ inline u16 f2b(float f) {
    __hip_bfloat16 h = __float2bfloat16(f);
    return *reinterpret_cast<u16*>(&h);
}
__device__ inline float b2f(u16 v) {
    return __uint_as_float(((unsigned)v) << 16);
}
__device__ inline void st_out(float* p, float v) { *p = v; }
__device__ inline void st_out(u16* p, float v)   { *p = f2b(v); }

// ---------------------------------------------------------------------------
// K0: prep. blocks 0-191: transpose-cast weights -> Wt [1024][512] bf16
// (rows 0-511 Wq^T | 512-767 Wk^T | 768-1023 Wv^T), Wot [512][512] = Wo^T.
// blocks 192-703: cast x -> xb bf16 (8 elems/thread, vectorized).
// ---------------------------------------------------------------------------
__global__ __launch_bounds__(256) void prep(const float* __restrict__ x,
    const float* __restrict__ Wq, const float* __restrict__ Wk,
    const float* __restrict__ Wv, const float* __restrict__ Wo,
    u16* __restrict__ xb, u16* __restrict__ Wt, u16* __restrict__ Wot)
{
    const int tid = threadIdx.x, bid = blockIdx.x;
    if (bid >= 192) {   // x cast
        int i = ((bid - 192) * 256 + tid) * 8;
        float4 v0 = *(const float4*)(x + i);
        float4 v1 = *(const float4*)(x + i + 4);
        ushort4 o0 = { f2b(v0.x), f2b(v0.y), f2b(v0.z), f2b(v0.w) };
        ushort4 o1 = { f2b(v1.x), f2b(v1.y), f2b(v1.z), f2b(v1.w) };
        *(ushort4*)(xb + i)     = o0;
        *(ushort4*)(xb + i + 4) = o1;
        return;
    }
    __shared__ u16 Tsh[64][72];
    const float* src; u16* dst; int N, base, kt, nt;
    if (bid < 64)       { src = Wq; dst = Wt;  N = 512; base = 0;   kt = bid >> 3;       nt = bid & 7; }
    else if (bid < 96)  { src = Wk; dst = Wt;  N = 256; base = 512; kt = (bid-64) >> 2;  nt = (bid-64) & 3; }
    else if (bid < 128) { src = Wv; dst = Wt;  N = 256; base = 768; kt = (bid-96) >> 2;  nt = (bid-96) & 3; }
    else                { src = Wo; dst = Wot; N = 512; base = 0;   kt = (bid-128) >> 3; nt = (bid-128) & 7; }
    const int k0 = kt * 64, n0 = nt * 64;
    const int r = tid >> 2, c0 = (tid & 3) * 16;
#pragma unroll
    for (int j = 0; j < 4; ++j) {
        float4 v = *(const float4*)(src + (size_t)(k0 + r) * N + n0 + c0 + j * 4);
        Tsh[c0 + j*4 + 0][r] = f2b(v.x);
        Tsh[c0 + j*4 + 1][r] = f2b(v.y);
        Tsh[c0 + j*4 + 2][r] = f2b(v.z);
        Tsh[c0 + j*4 + 3][r] = f2b(v.w);
    }
    __syncthreads();
    const int n = tid >> 2, kc = (tid & 3) * 16;
    u16* op = dst + (size_t)(base + n0 + n) * 512 + k0 + kc;
    *(s16x8*)(op)     = *(const s16x8*)&Tsh[n][kc];
    *(s16x8*)(op + 8) = *(const s16x8*)&Tsh[n][kc + 8];
}

// ---------------------------------------------------------------------------
// bf16 MFMA GEMM (verified R9 fast path): C[M x N] OutT = A bf16 @ Bt bf16.
// 64x64 tile / 4 waves (32x32 each), BK=64, 2-barrier loop, s16x8 staging.
// ---------------------------------------------------------------------------
template<typename OutT>
__global__ __launch_bounds__(256) void gemm_mfma(const u16* __restrict__ A,
    const u16* __restrict__ Bt, OutT* __restrict__ C, int ldc)
{
    __shared__ u16 Ash[64][72];
    __shared__ u16 Bsh[64][72];
    const int tid = threadIdx.x;
    const int m0b = blockIdx.y * 64, n0b = blockIdx.x * 64;
    const int lane = tid & 63, wv = tid >> 6;
    const int q = lane & 15, g = lane >> 4;
    const int wm = (wv & 1) * 32, wn = (wv >> 1) * 32;
    const int sr = tid >> 2, sc = (tid & 3) * 16;
    f32x4 acc[2][2] = {{{0,0,0,0},{0,0,0,0}},{{0,0,0,0},{0,0,0,0}}};
    for (int k0 = 0; k0 < 512; k0 += 64) {
        s16x8 a0 = *(const s16x8*)(A  + (size_t)(m0b + sr) * 512 + k0 + sc);
        s16x8 a1 = *(const s16x8*)(A  + (size_t)(m0b + sr) * 512 + k0 + sc + 8);
        s16x8 b0 = *(const s16x8*)(Bt + (size_t)(n0b + sr) * 512 + k0 + sc);
        s16x8 b1 = *(const s16x8*)(Bt + (size_t)(n0b + sr) * 512 + k0 + sc + 8);
        __syncthreads();
        *(s16x8*)&Ash[sr][sc]     = a0;
        *(s16x8*)&Ash[sr][sc + 8] = a1;
        *(s16x8*)&Bsh[sr][sc]     = b0;
        *(s16x8*)&Bsh[sr][sc + 8] = b1;
        __syncthreads();
#pragma unroll
        for (int kk = 0; kk < 64; kk += 32) {
            s16x8 af0 = *(const s16x8*)&Ash[wm + q][kk + g*8];
            s16x8 af1 = *(const s16x8*)&Ash[wm + 16 + q][kk + g*8];
            s16x8 bf0 = *(const s16x8*)&Bsh[wn + q][kk + g*8];
            s16x8 bf1 = *(const s16x8*)&Bsh[wn + 16 + q][kk + g*8];
            acc[0][0] = __builtin_amdgcn_mfma_f32_16x16x32_bf16(af0, bf0, acc[0][0], 0, 0, 0);
            acc[0][1] = __builtin_amdgcn_mfma_f32_16x16x32_bf16(af0, bf1, acc[0][1], 0, 0, 0);
            acc[1][0] = __builtin_amdgcn_mfma_f32_16x16x32_bf16(af1, bf0, acc[1][0], 0, 0, 0);
            acc[1][1] = __builtin_amdgcn_mfma_f32_16x16x32_bf16(af1, bf1, acc[1][1], 0, 0, 0);
        }
    }
#pragma unroll
    for (int mt = 0; mt < 2; ++mt)
#pragma unroll
        for (int nt = 0; nt < 2; ++nt)
#pragma unroll
            for (int r = 0; r < 4; ++r)
                st_out(&C[(size_t)(m0b + wm + mt*16 + g*4 + r) * ldc + n0b + wn + nt*16 + q],
                       acc[mt][nt][r]);
}

// ---------------------------------------------------------------------------
// swa: MFMA sliding-window attention with FUSED RoPE+RMS.
// Input qkvb bf16 [T][1024] = q(512)|k(256)|v(256), PRE-rope.
// K: rope+rms applied during LDS staging (8 lanes/row; pair d<->d+32 via
//    shfl_xor(4); rms reduce via shfl_xor(1,2,4)).
// Q: rope+rms in-register at fragment load (pair is lane-local across
//    qf0/qf1; rms reduce via shfl_xor(16,32) over the row's 4 g-lanes).
// V: plain bf16 (GEMM already cast), transposed into Vt (stride 202).
// Then verified path: S^T = K·Q^T; P^T -> O^T = V^T·P^T; LDS transpose out.
// ---------------------------------------------------------------------------
__global__ __launch_bounds__(256) void swa_mfma(const u16* __restrict__ qkvb,
    const float* __restrict__ cosT, const float* __restrict__ sinT,
    const float* __restrict__ qw, const float* __restrict__ kw,
    u16* __restrict__ attb)
{
    __shared__ u16 Ksh[192][72];
    __shared__ u16 Vt[64][202];
    const int tid = threadIdx.x;
    const int h = blockIdx.y, kvh = h >> 1;
    const int t0 = blockIdx.x * 64;
    // ---- K staging + rope + rms ----
    for (int i = 0; i < 6; ++i) {
        int idx = i * 256 + tid;
        int j = idx >> 3, e = idx & 7, d0 = e * 8;
        int kt = t0 - 127 + j;
        if (kt < 0) {
            s16x8 z = {0,0,0,0,0,0,0,0};
            *(s16x8*)&Ksh[j][d0] = z;
        } else {
            s16x8 raw = *(const s16x8*)(qkvb + (size_t)kt * 1024 + 512 + kvh * 64 + d0);
            float kv[8], ov[8];
#pragma unroll
            for (int ii = 0; ii < 8; ++ii) kv[ii] = b2f((u16)raw[ii]);
#pragma unroll
            for (int ii = 0; ii < 8; ++ii) ov[ii] = __shfl_xor(kv[ii], 4);
            const float* cp = cosT + kt * 32 + (e & 3) * 8;
            const float* sp = sinT + kt * 32 + (e & 3) * 8;
            float4 c0 = *(const float4*)(cp),     c1 = *(const float4*)(cp + 4);
            float4 s0 = *(const float4*)(sp),     s1 = *(const float4*)(sp + 4);
            float cf[8] = {c0.x,c0.y,c0.z,c0.w,c1.x,c1.y,c1.z,c1.w};
            float sf[8] = {s0.x,s0.y,s0.z,s0.w,s1.x,s1.y,s1.z,s1.w};
            const bool lo = (e < 4);
            float r[8]; float ssl = 0.f;
#pragma unroll
            for (int ii = 0; ii < 8; ++ii) {
                r[ii] = lo ? (kv[ii]*cf[ii] - ov[ii]*sf[ii])
                           : (kv[ii]*cf[ii] + ov[ii]*sf[ii]);
                ssl += r[ii] * r[ii];
            }
            ssl += __shfl_xor(ssl, 1);
            ssl += __shfl_xor(ssl, 2);
            ssl += __shfl_xor(ssl, 4);
            float scale = rsqrtf(ssl * (1.0f / 64.0f) + 1e-6f);
            float4 w0 = *(const float4*)(kw + d0), w1 = *(const float4*)(kw + d0 + 4);
            float wf[8] = {w0.x,w0.y,w0.z,w0.w,w1.x,w1.y,w1.z,w1.w};
            s16x8 outv;
#pragma unroll
            for (int ii = 0; ii < 8; ++ii) outv[ii] = (short)f2b(r[ii] * scale * wf[ii]);
            *(s16x8*)&Ksh[j][d0] = outv;
        }
    }
    // ---- V staging (transposed, stride 202) ----
    for (int cch = 0; cch < 6; ++cch) {
        int w  = cch * 32 + (tid & 31);
        int d0 = (tid >> 5) * 8;
        int kt = t0 - 127 + w;
        s16x8 val = {0,0,0,0,0,0,0,0};
        if (kt >= 0) val = *(const s16x8*)(qkvb + (size_t)kt * 1024 + 768 + kvh * 64 + d0);
#pragma unroll
        for (int jj = 0; jj < 8; ++jj) Vt[d0 + jj][w] = ((const u16*)&val)[jj];
    }
    // ---- Q fragment + rope + rms (in-register, before barrier) ----
    const int wv = tid >> 6, lane = tid & 63;
    const int q = lane & 15, g = lane >> 4;
    const int tw = t0 + wv * 16;
    const int t = tw + q;
    s16x8 qf0, qf1;
    {
        const u16* qp = qkvb + (size_t)t * 1024 + h * 64;
        s16x8 q0r = *(const s16x8*)(qp + g * 8);
        s16x8 q1r = *(const s16x8*)(qp + 32 + g * 8);
        const float* cp = cosT + t * 32 + g * 8;
        const float* sp = sinT + t * 32 + g * 8;
        float4 c0 = *(const float4*)(cp), c1 = *(const float4*)(cp + 4);
        float4 s0 = *(const float4*)(sp), s1 = *(const float4*)(sp + 4);
        float cf[8] = {c0.x,c0.y,c0.z,c0.w,c1.x,c1.y,c1.z,c1.w};
        float sf[8] = {s0.x,s0.y,s0.z,s0.w,s1.x,s1.y,s1.z,s1.w};
        float rl[8], rh[8]; float ssl = 0.f;
#pragma unroll
        for (int ii = 0; ii < 8; ++ii) {
            float ql = b2f((u16)q0r[ii]), qh = b2f((u16)q1r[ii]);
            rl[ii] = ql * cf[ii] - qh * sf[ii];
            rh[ii] = qh * cf[ii] + ql * sf[ii];
            ssl += rl[ii]*rl[ii] + rh[ii]*rh[ii];
        }
        ssl += __shfl_xor(ssl, 16);
        ssl += __shfl_xor(ssl, 32);
        float scale = rsqrtf(ssl * (1.0f / 64.0f) + 1e-6f);
        float4 wl0 = *(const float4*)(qw + g * 8), wl1 = *(const float4*)(qw + g * 8 + 4);
        float4 wh0 = *(const float4*)(qw + 32 + g * 8), wh1 = *(const float4*)(qw + 32 + g * 8 + 4);
        float wlo[8] = {wl0.x,wl0.y,wl0.z,wl0.w,wl1.x,wl1.y,wl1.z,wl1.w};
        float whi[8] = {wh0.x,wh0.y,wh0.z,wh0.w,wh1.x,wh1.y,wh1.z,wh1.w};
#pragma unroll
        for (int ii = 0; ii < 8; ++ii) {
            qf0[ii] = (short)f2b(rl[ii] * scale * wlo[ii]);
            qf1[ii] = (short)f2b(rh[ii] * scale * whi[ii]);
        }
    }
    __syncthreads();
    // ---- QK^T -> softmax -> PV (verified R9 path) ----
    float s[9][4];
    float mx = -INFINITY;
    for (int wt = 0; wt < 9; ++wt) {
        int ldsrow = wv * 16 + wt * 16 + q;
        s16x8 kf0 = *(const s16x8*)&Ksh[ldsrow][g * 8];
        s16x8 kf1 = *(const s16x8*)&Ksh[ldsrow][32 + g * 8];
        f32x4 accv = {0, 0, 0, 0};
        accv = __builtin_amdgcn_mfma_f32_16x16x32_bf16(kf0, qf0, accv, 0, 0, 0);
        accv = __builtin_amdgcn_mfma_f32_16x16x32_bf16(kf1, qf1, accv, 0, 0, 0);
#pragma unroll
        for (int r = 0; r < 4; ++r) {
            int woff = wt * 16 + g * 4 + r;
            int key  = tw - 127 + woff;
            bool ok = (woff >= q) && (woff <= q + 127) && (key >= 0);
            float sv = ok ? accv[r] * 0.125f : -INFINITY;
            s[wt][r] = sv;
            mx = fmaxf(mx, sv);
        }
    }
    mx = fmaxf(mx, __shfl_xor(mx, 16));
    mx = fmaxf(mx, __shfl_xor(mx, 32));
    float sum = 0.f;
    s16x4 pb[9];
    for (int wt = 0; wt < 9; ++wt) {
#pragma unroll
        for (int r = 0; r < 4; ++r) {
            float p = __expf(s[wt][r] - mx);
            sum += p;
            pb[wt][r] = (short)f2b(p);
        }
    }
    sum += __shfl_xor(sum, 16);
    sum += __shfl_xor(sum, 32);
    float inv = 1.0f / sum;
    f32x4 oacc[4];
#pragma unroll
    for (int dt = 0; dt < 4; ++dt) {
        f32x4 a = {0, 0, 0, 0};
        for (int wt = 0; wt < 9; ++wt) {
            int col = wv * 16 + wt * 16 + g * 4;
            s16x4 vf = *(const s16x4*)&Vt[dt * 16 + q][col];
            a = __builtin_amdgcn_mfma_f32_16x16x16bf16_1k(vf, pb[wt], a, 0, 0, 0);
        }
        oacc[dt] = a;
    }
    __syncthreads();
    float (*Osh)[16][68] = (float (*)[16][68])&Ksh[0][0];
#pragma unroll
    for (int dt = 0; dt < 4; ++dt)
#pragma unroll
        for (int r = 0; r < 4; ++r)
            Osh[wv][q][dt * 16 + g * 4 + r] = oacc[dt][r] * inv;
    __syncthreads();
    const int qq = lane >> 2, dd0 = (lane & 3) * 16;
    u16* op = attb + (size_t)(tw + qq) * 512 + h * 64 + dd0;
#pragma unroll
    for (int jj = 0; jj < 4; ++jj) {
        float4 vvv = *(const float4*)&Osh[wv][qq][dd0 + jj * 4];
        ushort4 ov = { f2b(vvv.x), f2b(vvv.y), f2b(vvv.z), f2b(vvv.w) };
        *(ushort4*)(op + jj * 4) = ov;
    }
}

// ---------------------------------------------------------------------------
// Workspace: xb [2048*512 u16] | Wt [1024*512] | Wot [512*512] |
//            qkvb bf16 [2048*1024] | attb [2048*512]   ≈ 9.5 MB
// ---------------------------------------------------------------------------
extern "C" void kernel_launch(void* const* d_in, const int* in_sizes, int n_in,
                              void* d_out, int out_size, void* d_ws, size_t ws_size,
                              hipStream_t stream)
{
    const float* x    = (const float*)d_in[0];
    const float* Wq   = (const float*)d_in[1];
    const float* Wk   = (const float*)d_in[2];
    const float* Wv   = (const float*)d_in[3];
    const float* Wo   = (const float*)d_in[4];
    const float* qw   = (const float*)d_in[5];
    const float* kw   = (const float*)d_in[6];
    const float* cosT = (const float*)d_in[7];
    const float* sinT = (const float*)d_in[8];

    u16* ws   = (u16*)d_ws;
    u16* xb   = ws;                               // 2048*512
    u16* Wt   = xb   + (size_t)2048 * 512;        // 1024*512
    u16* Wot  = Wt   + (size_t)1024 * 512;        // 512*512
    u16* qkvb = Wot  + (size_t)512 * 512;         // 2048*1024 bf16
    u16* attb = qkvb + (size_t)2048 * 1024;       // 2048*512

    dim3 blk(256);
    hipLaunchKernelGGL(prep, dim3(704), blk, 0, stream, x, Wq, Wk, Wv, Wo, xb, Wt, Wot);
    hipLaunchKernelGGL((gemm_mfma<u16>), dim3(16, 32), blk, 0, stream, xb, Wt, qkvb, 1024);
    hipLaunchKernelGGL(swa_mfma, dim3(32, 8), blk, 0, stream,
                       qkvb, cosT, sinT, qw, kw, attb);
    hipLaunchKernelGGL((gemm_mfma<float>), dim3(8, 32), blk, 0, stream,
                       attb, Wot, (float*)d_out, 512);
}